// Round 5
// baseline (60.840 us; speedup 1.0000x reference)
//
#include <hip/hip_runtime.h>

// CenterLoss: loss = 0.5 * LAMBDA_C * mean_b ||hidden[b] - centers[y[b]]||^2
// B=1024, C=1000, D=512 (but written generally; assumes D % 4 == 0).

__global__ void cl_partial_kernel(const int* __restrict__ y,
                                  const float4* __restrict__ hidden,
                                  const float4* __restrict__ centers,
                                  float* __restrict__ part,
                                  int d4) {
    const int b = blockIdx.x;     // sample index
    const int t = threadIdx.x;    // 0 .. d4-1 (d4 = D/4)
    const int cls = y[b];

    float4 h = hidden[(size_t)b * d4 + t];
    float4 c = centers[(size_t)cls * d4 + t];
    float dx = h.x - c.x;
    float dy = h.y - c.y;
    float dz = h.z - c.z;
    float dw = h.w - c.w;
    float s = dx * dx + dy * dy + dz * dz + dw * dw;

    // 64-lane wave reduction
    #pragma unroll
    for (int off = 32; off > 0; off >>= 1)
        s += __shfl_down(s, off, 64);

    // combine waves within the block (blockDim.x / 64 waves, <= 16)
    __shared__ float wsum[16];
    const int wid = t >> 6;
    if ((t & 63) == 0) wsum[wid] = s;
    __syncthreads();
    if (t == 0) {
        const int nw = (blockDim.x + 63) >> 6;
        float acc = 0.f;
        for (int i = 0; i < nw; ++i) acc += wsum[i];
        part[b] = acc;
    }
}

__global__ void cl_reduce_kernel(const float* __restrict__ part,
                                 float* __restrict__ out,
                                 int n, float scale) {
    float s = 0.f;
    for (int i = threadIdx.x; i < n; i += blockDim.x)
        s += part[i];

    #pragma unroll
    for (int off = 32; off > 0; off >>= 1)
        s += __shfl_down(s, off, 64);

    __shared__ float wsum[16];
    const int wid = threadIdx.x >> 6;
    if ((threadIdx.x & 63) == 0) wsum[wid] = s;
    __syncthreads();
    if (threadIdx.x == 0) {
        const int nw = (blockDim.x + 63) >> 6;
        float acc = 0.f;
        for (int i = 0; i < nw; ++i) acc += wsum[i];
        out[0] = acc * scale;
    }
}

extern "C" void kernel_launch(void* const* d_in, const int* in_sizes, int n_in,
                              void* d_out, int out_size, void* d_ws, size_t ws_size,
                              hipStream_t stream) {
    const int*   y       = (const int*)d_in[0];
    const float* hidden  = (const float*)d_in[1];
    const float* centers = (const float*)d_in[2];
    float*       out     = (float*)d_out;
    float*       part    = (float*)d_ws;   // B floats of scratch

    const int B  = in_sizes[0];
    const int D  = in_sizes[1] / B;        // 512
    const int d4 = D / 4;                  // 128 threads per block (2 waves)

    cl_partial_kernel<<<B, d4, 0, stream>>>(
        y, (const float4*)hidden, (const float4*)centers, part, d4);

    const float scale = 0.5f / (float)B;   // LAMBDA_C = 1.0
    cl_reduce_kernel<<<1, 256, 0, stream>>>(part, out, B, scale);
}